// Round 1
// baseline (216.034 us; speedup 1.0000x reference)
//
#include <hip/hip_runtime.h>
#include <stdint.h>

#define Bsz  8192
#define DMOD 512
#define NE   4
#define NP   1024
#define NF   2048

typedef float  f32x4  __attribute__((ext_vector_type(4)));
typedef __bf16 bf16x8 __attribute__((ext_vector_type(8)));
typedef unsigned short u16x8 __attribute__((ext_vector_type(8)));

__device__ __forceinline__ unsigned short f32_bf16(float f) {
  unsigned int u = __float_as_uint(f);
  u += 0x7FFFu + ((u >> 16) & 1u);   // round-to-nearest-even
  return (unsigned short)(u >> 16);
}

// ---------------- kernel 1: concat + cvt x_mods -> fused_bf16 [B][F] ----------------
__global__ __launch_bounds__(256) void fuse_cvt(
    const float* __restrict__ x0, const float* __restrict__ x1,
    const float* __restrict__ x2, const float* __restrict__ x3,
    unsigned short* __restrict__ fusedB)
{
  size_t i8 = ((size_t)blockIdx.x * 256 + threadIdx.x) * 8;   // grid exactly covers B*F
  int f = (int)(i8 & (NF - 1));
  size_t b = i8 >> 11;
  const float* x = (f < 1024) ? (f < 512 ? x0 : x1) : (f < 1536 ? x2 : x3);
  const float* src = x + b * DMOD + (f & 511);
  float4 v0 = *(const float4*)src;
  float4 v1 = *(const float4*)(src + 4);
  u16x8 o;
  o[0] = f32_bf16(v0.x); o[1] = f32_bf16(v0.y); o[2] = f32_bf16(v0.z); o[3] = f32_bf16(v0.w);
  o[4] = f32_bf16(v1.x); o[5] = f32_bf16(v1.y); o[6] = f32_bf16(v1.z); o[7] = f32_bf16(v1.w);
  *(u16x8*)(fusedB + i8) = o;
}

// ---------------- kernel 2: We [E][F][P] f32 -> We_T [E][P][F] bf16 ----------------
__global__ __launch_bounds__(256) void we_transpose(
    const float* __restrict__ We, unsigned short* __restrict__ WeT)
{
  __shared__ float t[64][65];
  const int e  = blockIdx.z;
  const int tf = blockIdx.x * 64;
  const int tp = blockIdx.y * 64;
  const int t4 = threadIdx.x * 4;
  const float* src = We + ((size_t)e * NF + tf) * NP + tp;
  #pragma unroll
  for (int i = 0; i < 4; ++i) {
    int li = i * 1024 + t4;
    int r = li >> 6, c = li & 63;
    float4 v = *(const float4*)(src + (size_t)r * NP + c);
    t[c][r] = v.x; t[c+1][r] = v.y; t[c+2][r] = v.z; t[c+3][r] = v.w;
  }
  __syncthreads();
  unsigned short* dst = WeT + ((size_t)e * NP + tp) * NF + tf;
  #pragma unroll
  for (int i = 0; i < 4; ++i) {
    int li = i * 1024 + t4;
    int r = li >> 6, c = li & 63;
    ushort4 o;
    o.x = f32_bf16(t[r][c]);   o.y = f32_bf16(t[r][c+1]);
    o.z = f32_bf16(t[r][c+2]); o.w = f32_bf16(t[r][c+3]);
    *(ushort4*)(dst + (size_t)r * NF + c) = o;
  }
}

// ---------------- kernel 3: gate logits -> softmax -> top2 -> sparse weights ----------------
__global__ __launch_bounds__(256) void gate_kernel(
    const float* __restrict__ x0, const float* __restrict__ x1,
    const float* __restrict__ x2, const float* __restrict__ x3,
    const float* __restrict__ Wg, float* __restrict__ gw, double* __restrict__ lossAcc)
{
  const int row  = blockIdx.x * 4 + (threadIdx.x >> 6);
  const int lane = threadIdx.x & 63;
  float a0 = 0.f, a1 = 0.f, a2 = 0.f, a3 = 0.f;
  #pragma unroll
  for (int i = 0; i < 32; ++i) {
    const float* x = (i < 16) ? (i < 8 ? x0 : x1) : (i < 24 ? x2 : x3);
    int f = i * 64 + lane;
    float v = x[(size_t)row * DMOD + (f & 511)];
    a0 += v * Wg[f];
    a1 += v * Wg[NF + f];
    a2 += v * Wg[2 * NF + f];
    a3 += v * Wg[3 * NF + f];
  }
  #pragma unroll
  for (int off = 32; off; off >>= 1) {
    a0 += __shfl_xor(a0, off); a1 += __shfl_xor(a1, off);
    a2 += __shfl_xor(a2, off); a3 += __shfl_xor(a3, off);
  }
  if (lane == 0) {
    float m  = fmaxf(fmaxf(a0, a1), fmaxf(a2, a3));
    float e0 = expf(a0 - m), e1 = expf(a1 - m), e2 = expf(a2 - m), e3 = expf(a3 - m);
    float inv = 1.f / (e0 + e1 + e2 + e3);
    float p0 = e0 * inv, p1 = e1 * inv, p2 = e2 * inv, p3 = e3 * inv;
    int i1 = 0; float b1 = a0;
    if (a1 > b1) { b1 = a1; i1 = 1; }
    if (a2 > b1) { b1 = a2; i1 = 2; }
    if (a3 > b1) { b1 = a3; i1 = 3; }
    int i2 = -1; float b2 = -3.4e38f;
    if (i1 != 0 && a0 > b2) { b2 = a0; i2 = 0; }
    if (i1 != 1 && a1 > b2) { b2 = a1; i2 = 1; }
    if (i1 != 2 && a2 > b2) { b2 = a2; i2 = 2; }
    if (i1 != 3 && a3 > b2) { b2 = a3; i2 = 3; }
    gw[(size_t)row * 4 + 0] = (i1 == 0 || i2 == 0) ? p0 : 0.f;
    gw[(size_t)row * 4 + 1] = (i1 == 1 || i2 == 1) ? p1 : 0.f;
    gw[(size_t)row * 4 + 2] = (i1 == 2 || i2 == 2) ? p2 : 0.f;
    gw[(size_t)row * 4 + 3] = (i1 == 3 || i2 == 3) ? p3 : 0.f;
  }
  if (blockIdx.x == 0 && threadIdx.x == 0) *lossAcc = 0.0;
}

// ---------------- kernel 4: per-expert GEMM with gate-weighted fold + fused epilogue ----------------
__global__ __launch_bounds__(256, 2) void moe_gemm(
    const unsigned short* __restrict__ fusedB,   // [B][F] bf16
    const unsigned short* __restrict__ WeT,      // [E][P][F] bf16
    const float* __restrict__ gw,                // [B][E]
    const float* __restrict__ be,                // [E][P]
    const float* __restrict__ label,             // [B][P]
    float* __restrict__ out,                     // [0]=loss, [1..] preds
    double* __restrict__ lossAcc)
{
  __shared__ __align__(16) unsigned short As[128 * 64];
  __shared__ __align__(16) unsigned short Bs[128 * 64];
  __shared__ float red[4];

  const int tid  = threadIdx.x;
  const int l    = tid & 63;
  const int wave = tid >> 6;
  const int wr   = wave >> 1;
  const int wc   = wave & 1;
  const int brow = (int)blockIdx.y * 128;
  const int pcol = (int)blockIdx.x * 128;
  const int lrow = l & 15;
  const int g4   = l >> 4;

  f32x4 accT[4][4];
  #pragma unroll
  for (int m = 0; m < 4; ++m)
    #pragma unroll
    for (int n = 0; n < 4; ++n) accT[m][n] = f32x4{0.f, 0.f, 0.f, 0.f};

  for (int e = 0; e < NE; ++e) {
    f32x4 accE[4][4];
    #pragma unroll
    for (int m = 0; m < 4; ++m)
      #pragma unroll
      for (int n = 0; n < 4; ++n) accE[m][n] = f32x4{0.f, 0.f, 0.f, 0.f};

    const unsigned short* Bb = WeT + ((size_t)e * NP + pcol) * NF;

    for (int kt = 0; kt < NF / 64; ++kt) {
      const int k0 = kt * 64;
      __syncthreads();
      // stage 128x64 bf16 tiles, XOR-swizzled (chunk ^= row&7) to kill ds_read_b128 conflicts
      #pragma unroll
      for (int j = 0; j < 4; ++j) {
        const int ci  = j * 256 + tid;
        const int row = ci >> 3;
        const int c7  = ci & 7;
        const int sw  = (c7 ^ (row & 7)) * 8;
        u16x8 va = *(const u16x8*)(fusedB + (size_t)(brow + row) * NF + k0 + c7 * 8);
        u16x8 vb = *(const u16x8*)(Bb     + (size_t)row * NF        + k0 + c7 * 8);
        *(u16x8*)(As + row * 64 + sw) = va;
        *(u16x8*)(Bs + row * 64 + sw) = vb;
      }
      __syncthreads();
      #pragma unroll
      for (int ks = 0; ks < 2; ++ks) {
        bf16x8 af[4], bfr[4];
        #pragma unroll
        for (int m = 0; m < 4; ++m) {
          const int fr = wr * 64 + m * 16 + lrow;
          const int ch = ((g4 + ks * 4) ^ (fr & 7)) * 8;
          af[m] = __builtin_bit_cast(bf16x8, *(const u16x8*)(As + fr * 64 + ch));
        }
        #pragma unroll
        for (int n = 0; n < 4; ++n) {
          const int fr = wc * 64 + n * 16 + lrow;
          const int ch = ((g4 + ks * 4) ^ (fr & 7)) * 8;
          bfr[n] = __builtin_bit_cast(bf16x8, *(const u16x8*)(Bs + fr * 64 + ch));
        }
        #pragma unroll
        for (int m = 0; m < 4; ++m)
          #pragma unroll
          for (int n = 0; n < 4; ++n)
            accE[m][n] = __builtin_amdgcn_mfma_f32_16x16x32_bf16(af[m], bfr[n], accE[m][n], 0, 0, 0);
      }
    }
    // fold expert e into total with per-row gate weight (C/D row = g4*4 + reg)
    #pragma unroll
    for (int m = 0; m < 4; ++m) {
      #pragma unroll
      for (int r = 0; r < 4; ++r) {
        const int grow = brow + wr * 64 + m * 16 + g4 * 4 + r;
        const float wv = gw[(size_t)grow * NE + e];
        #pragma unroll
        for (int n = 0; n < 4; ++n) accT[m][n][r] += wv * accE[m][n][r];
      }
    }
  }

  // epilogue: bias, store preds, fused MSE partial
  float lsum = 0.f;
  #pragma unroll
  for (int m = 0; m < 4; ++m) {
    #pragma unroll
    for (int r = 0; r < 4; ++r) {
      const int grow = brow + wr * 64 + m * 16 + g4 * 4 + r;
      const float w0 = gw[(size_t)grow * NE + 0];
      const float w1 = gw[(size_t)grow * NE + 1];
      const float w2 = gw[(size_t)grow * NE + 2];
      const float w3 = gw[(size_t)grow * NE + 3];
      #pragma unroll
      for (int n = 0; n < 4; ++n) {
        const int gcol = pcol + wc * 64 + n * 16 + lrow;
        float bias = w0 * be[gcol] + w1 * be[NP + gcol] + w2 * be[2 * NP + gcol] + w3 * be[3 * NP + gcol];
        float pred = accT[m][n][r] + bias;
        out[1 + (size_t)grow * NP + gcol] = pred;
        float d = pred - label[(size_t)grow * NP + gcol];
        lsum += d * d;
      }
    }
  }
  #pragma unroll
  for (int off = 32; off; off >>= 1) lsum += __shfl_xor(lsum, off);
  if (l == 0) red[wave] = lsum;
  __syncthreads();
  if (tid == 0) {
    double s = (double)red[0] + (double)red[1] + (double)red[2] + (double)red[3];
    atomicAdd(lossAcc, s);
  }
}

// ---------------- kernel 5: finalize loss ----------------
__global__ void finalize_kernel(const double* __restrict__ lossAcc, float* __restrict__ out) {
  out[0] = (float)(*lossAcc * (1.0 / ((double)Bsz * (double)NP)));
}

extern "C" void kernel_launch(void* const* d_in, const int* in_sizes, int n_in,
                              void* d_out, int out_size, void* d_ws, size_t ws_size,
                              hipStream_t stream) {
  const float* x0    = (const float*)d_in[0];
  const float* x1    = (const float*)d_in[1];
  const float* x2    = (const float*)d_in[2];
  const float* x3    = (const float*)d_in[3];
  const float* label = (const float*)d_in[4];
  const float* Wg    = (const float*)d_in[5];
  const float* We    = (const float*)d_in[6];
  const float* be    = (const float*)d_in[7];
  float* out = (float*)d_out;

  char* ws = (char*)d_ws;
  unsigned short* WeT    = (unsigned short*)ws;                         // 16 MiB
  unsigned short* fusedB = (unsigned short*)(ws + ((size_t)16 << 20));  // 32 MiB
  float*  gw      = (float*)(ws + ((size_t)48 << 20));                  // 128 KiB
  double* lossAcc = (double*)(ws + ((size_t)49 << 20));                 // 8 B

  fuse_cvt<<<dim3((Bsz * NF) / (256 * 8)), 256, 0, stream>>>(x0, x1, x2, x3, fusedB);
  we_transpose<<<dim3(NF / 64, NP / 64, NE), 256, 0, stream>>>(We, WeT);
  gate_kernel<<<dim3(Bsz / 4), 256, 0, stream>>>(x0, x1, x2, x3, Wg, gw, lossAcc);
  moe_gemm<<<dim3(NP / 128, Bsz / 128), 256, 0, stream>>>(fusedB, WeT, gw, be, label, out, lossAcc);
  finalize_kernel<<<1, 1, 0, stream>>>(lossAcc, out);
}

// Round 2
// 200.899 us; speedup vs baseline: 1.0753x; 1.0753x over previous
//
#include <hip/hip_runtime.h>
#include <stdint.h>

#define Bsz  8192
#define DMOD 512
#define NE   4
#define NP   1024
#define NF   2048

typedef float  f32x4  __attribute__((ext_vector_type(4)));
typedef __bf16 bf16x8 __attribute__((ext_vector_type(8)));
typedef unsigned short u16x8 __attribute__((ext_vector_type(8)));

typedef __attribute__((address_space(3))) void       lds_void;
typedef const __attribute__((address_space(1))) void glb_void;
#define GLOAD16(gp, lp) \
  __builtin_amdgcn_global_load_lds((glb_void*)(gp), (lds_void*)(lp), 16, 0, 0)

__device__ __forceinline__ unsigned short f32_bf16(float f) {
  unsigned int u = __float_as_uint(f);
  u += 0x7FFFu + ((u >> 16) & 1u);   // round-to-nearest-even
  return (unsigned short)(u >> 16);
}

// ---------------- kernel 1: concat + cvt x_mods -> fused_bf16 [B][F] ----------------
__global__ __launch_bounds__(256) void fuse_cvt(
    const float* __restrict__ x0, const float* __restrict__ x1,
    const float* __restrict__ x2, const float* __restrict__ x3,
    unsigned short* __restrict__ fusedB)
{
  size_t i8 = ((size_t)blockIdx.x * 256 + threadIdx.x) * 8;   // grid exactly covers B*F
  int f = (int)(i8 & (NF - 1));
  size_t b = i8 >> 11;
  const float* x = (f < 1024) ? (f < 512 ? x0 : x1) : (f < 1536 ? x2 : x3);
  const float* src = x + b * DMOD + (f & 511);
  float4 v0 = *(const float4*)src;
  float4 v1 = *(const float4*)(src + 4);
  u16x8 o;
  o[0] = f32_bf16(v0.x); o[1] = f32_bf16(v0.y); o[2] = f32_bf16(v0.z); o[3] = f32_bf16(v0.w);
  o[4] = f32_bf16(v1.x); o[5] = f32_bf16(v1.y); o[6] = f32_bf16(v1.z); o[7] = f32_bf16(v1.w);
  *(u16x8*)(fusedB + i8) = o;
}

// ---------------- kernel 2: We [E][F][P] f32 -> We_T [E][P][F] bf16 ----------------
__global__ __launch_bounds__(256) void we_transpose(
    const float* __restrict__ We, unsigned short* __restrict__ WeT)
{
  __shared__ float t[64][65];
  const int e  = blockIdx.z;
  const int tf = blockIdx.x * 64;
  const int tp = blockIdx.y * 64;
  const int t4 = threadIdx.x * 4;
  const float* src = We + ((size_t)e * NF + tf) * NP + tp;
  #pragma unroll
  for (int i = 0; i < 4; ++i) {
    int li = i * 1024 + t4;
    int r = li >> 6, c = li & 63;
    float4 v = *(const float4*)(src + (size_t)r * NP + c);
    t[c][r] = v.x; t[c+1][r] = v.y; t[c+2][r] = v.z; t[c+3][r] = v.w;
  }
  __syncthreads();
  unsigned short* dst = WeT + ((size_t)e * NP + tp) * NF + tf;
  #pragma unroll
  for (int i = 0; i < 4; ++i) {
    int li = i * 1024 + t4;
    int r = li >> 6, c = li & 63;
    ushort4 o;
    o.x = f32_bf16(t[r][c]);   o.y = f32_bf16(t[r][c+1]);
    o.z = f32_bf16(t[r][c+2]); o.w = f32_bf16(t[r][c+3]);
    *(ushort4*)(dst + (size_t)r * NF + c) = o;
  }
}

// ---------------- kernel 3: gate logits -> softmax -> top2 -> sparse weights ----------------
__global__ __launch_bounds__(256) void gate_kernel(
    const float* __restrict__ x0, const float* __restrict__ x1,
    const float* __restrict__ x2, const float* __restrict__ x3,
    const float* __restrict__ Wg, float* __restrict__ gw, double* __restrict__ lossAcc)
{
  const int row  = blockIdx.x * 4 + (threadIdx.x >> 6);
  const int lane = threadIdx.x & 63;
  float a0 = 0.f, a1 = 0.f, a2 = 0.f, a3 = 0.f;
  #pragma unroll
  for (int i = 0; i < 32; ++i) {
    const float* x = (i < 16) ? (i < 8 ? x0 : x1) : (i < 24 ? x2 : x3);
    int f = i * 64 + lane;
    float v = x[(size_t)row * DMOD + (f & 511)];
    a0 += v * Wg[f];
    a1 += v * Wg[NF + f];
    a2 += v * Wg[2 * NF + f];
    a3 += v * Wg[3 * NF + f];
  }
  #pragma unroll
  for (int off = 32; off; off >>= 1) {
    a0 += __shfl_xor(a0, off); a1 += __shfl_xor(a1, off);
    a2 += __shfl_xor(a2, off); a3 += __shfl_xor(a3, off);
  }
  if (lane == 0) {
    float m  = fmaxf(fmaxf(a0, a1), fmaxf(a2, a3));
    float e0 = expf(a0 - m), e1 = expf(a1 - m), e2 = expf(a2 - m), e3 = expf(a3 - m);
    float inv = 1.f / (e0 + e1 + e2 + e3);
    float p0 = e0 * inv, p1 = e1 * inv, p2 = e2 * inv, p3 = e3 * inv;
    int i1 = 0; float b1 = a0;
    if (a1 > b1) { b1 = a1; i1 = 1; }
    if (a2 > b1) { b1 = a2; i1 = 2; }
    if (a3 > b1) { b1 = a3; i1 = 3; }
    int i2 = -1; float b2 = -3.4e38f;
    if (i1 != 0 && a0 > b2) { b2 = a0; i2 = 0; }
    if (i1 != 1 && a1 > b2) { b2 = a1; i2 = 1; }
    if (i1 != 2 && a2 > b2) { b2 = a2; i2 = 2; }
    if (i1 != 3 && a3 > b2) { b2 = a3; i2 = 3; }
    gw[(size_t)row * 4 + 0] = (i1 == 0 || i2 == 0) ? p0 : 0.f;
    gw[(size_t)row * 4 + 1] = (i1 == 1 || i2 == 1) ? p1 : 0.f;
    gw[(size_t)row * 4 + 2] = (i1 == 2 || i2 == 2) ? p2 : 0.f;
    gw[(size_t)row * 4 + 3] = (i1 == 3 || i2 == 3) ? p3 : 0.f;
  }
  if (blockIdx.x == 0 && threadIdx.x == 0) *lossAcc = 0.0;
}

// ---------------- kernel 4: per-expert GEMM, global_load_lds staging, fused epilogue ----------------
// LDS layout: linear [128][64] ushort; logical chunk c of row r lives at LDS chunk c^(r&7).
// Achieved by inverse-swizzling the GLOBAL source chunk (rule #21): lane l loads global
// chunk (l&7)^(row&7) into linear LDS slot (row, l&7). Read side XORs identically.
__global__ __launch_bounds__(256, 2) void moe_gemm(
    const unsigned short* __restrict__ fusedB,   // [B][F] bf16
    const unsigned short* __restrict__ WeT,      // [E][P][F] bf16
    const float* __restrict__ gw,                // [B][E]
    const float* __restrict__ be,                // [E][P]
    const float* __restrict__ label,             // [B][P]
    float* __restrict__ out,                     // [0]=loss, [1..] preds
    double* __restrict__ lossAcc)
{
  __shared__ __align__(16) unsigned short As[128 * 64];
  __shared__ __align__(16) unsigned short Bs[128 * 64];
  __shared__ float red[4];

  const int tid  = threadIdx.x;
  const int l    = tid & 63;
  const int wave = tid >> 6;
  const int wr   = wave >> 1;
  const int wc   = wave & 1;
  const int brow = (int)blockIdx.y * 128;
  const int pcol = (int)blockIdx.x * 128;
  const int lrow = l & 15;
  const int g4   = l >> 4;
  const int lr8  = l >> 3;   // lane's row within an 8-row staging stripe
  const int lc8  = l & 7;    // lane's linear LDS chunk within the row

  f32x4 accT[4][4];
  #pragma unroll
  for (int m = 0; m < 4; ++m)
    #pragma unroll
    for (int n = 0; n < 4; ++n) accT[m][n] = f32x4{0.f, 0.f, 0.f, 0.f};

  for (int e = 0; e < NE; ++e) {
    f32x4 accE[4][4];
    #pragma unroll
    for (int m = 0; m < 4; ++m)
      #pragma unroll
      for (int n = 0; n < 4; ++n) accE[m][n] = f32x4{0.f, 0.f, 0.f, 0.f};

    const unsigned short* Bb = WeT + ((size_t)e * NP + pcol) * NF;

    for (int kt = 0; kt < NF / 64; ++kt) {
      const int k0 = kt * 64;
      __syncthreads();   // previous tile's reads complete before overwrite
      // stage via global_load_lds width=16: 8 wave-issues (4 A + 4 B), 1 KiB each
      #pragma unroll
      for (int i = 0; i < 4; ++i) {
        const int r0   = wave * 32 + i * 8;          // wave-uniform stripe base
        const int trow = r0 + lr8;
        const int ch   = lc8 ^ (trow & 7);           // inverse-swizzled source chunk
        GLOAD16(fusedB + (size_t)(brow + trow) * NF + k0 + ch * 8,
                (char*)As + r0 * 128);
      }
      #pragma unroll
      for (int i = 0; i < 4; ++i) {
        const int r0   = wave * 32 + i * 8;
        const int trow = r0 + lr8;
        const int ch   = lc8 ^ (trow & 7);
        GLOAD16(Bb + (size_t)trow * NF + k0 + ch * 8,
                (char*)Bs + r0 * 128);
      }
      __syncthreads();   // compiler drains vmcnt(0) before s_barrier -> LDS ready
      #pragma unroll
      for (int ks = 0; ks < 2; ++ks) {
        bf16x8 af[4], bfr[4];
        #pragma unroll
        for (int m = 0; m < 4; ++m) {
          const int fr = wr * 64 + m * 16 + lrow;
          const int ch = ((g4 + ks * 4) ^ (fr & 7)) * 8;
          af[m] = __builtin_bit_cast(bf16x8, *(const u16x8*)(As + fr * 64 + ch));
        }
        #pragma unroll
        for (int n = 0; n < 4; ++n) {
          const int fr = wc * 64 + n * 16 + lrow;
          const int ch = ((g4 + ks * 4) ^ (fr & 7)) * 8;
          bfr[n] = __builtin_bit_cast(bf16x8, *(const u16x8*)(Bs + fr * 64 + ch));
        }
        #pragma unroll
        for (int m = 0; m < 4; ++m)
          #pragma unroll
          for (int n = 0; n < 4; ++n)
            accE[m][n] = __builtin_amdgcn_mfma_f32_16x16x32_bf16(af[m], bfr[n], accE[m][n], 0, 0, 0);
      }
    }
    // fold expert e into total with per-row gate weight (C/D row = g4*4 + reg)
    #pragma unroll
    for (int m = 0; m < 4; ++m) {
      #pragma unroll
      for (int r = 0; r < 4; ++r) {
        const int grow = brow + wr * 64 + m * 16 + g4 * 4 + r;
        const float wv = gw[(size_t)grow * NE + e];
        #pragma unroll
        for (int n = 0; n < 4; ++n) accT[m][n][r] += wv * accE[m][n][r];
      }
    }
  }

  // epilogue: bias, store preds, fused MSE partial
  float lsum = 0.f;
  #pragma unroll
  for (int m = 0; m < 4; ++m) {
    #pragma unroll
    for (int r = 0; r < 4; ++r) {
      const int grow = brow + wr * 64 + m * 16 + g4 * 4 + r;
      const float w0 = gw[(size_t)grow * NE + 0];
      const float w1 = gw[(size_t)grow * NE + 1];
      const float w2 = gw[(size_t)grow * NE + 2];
      const float w3 = gw[(size_t)grow * NE + 3];
      #pragma unroll
      for (int n = 0; n < 4; ++n) {
        const int gcol = pcol + wc * 64 + n * 16 + lrow;
        float bias = w0 * be[gcol] + w1 * be[NP + gcol] + w2 * be[2 * NP + gcol] + w3 * be[3 * NP + gcol];
        float pred = accT[m][n][r] + bias;
        out[1 + (size_t)grow * NP + gcol] = pred;
        float d = pred - label[(size_t)grow * NP + gcol];
        lsum += d * d;
      }
    }
  }
  #pragma unroll
  for (int off = 32; off; off >>= 1) lsum += __shfl_xor(lsum, off);
  if (l == 0) red[wave] = lsum;
  __syncthreads();
  if (tid == 0) {
    double s = (double)red[0] + (double)red[1] + (double)red[2] + (double)red[3];
    atomicAdd(lossAcc, s);
  }
}

// ---------------- kernel 5: finalize loss ----------------
__global__ void finalize_kernel(const double* __restrict__ lossAcc, float* __restrict__ out) {
  out[0] = (float)(*lossAcc * (1.0 / ((double)Bsz * (double)NP)));
}

extern "C" void kernel_launch(void* const* d_in, const int* in_sizes, int n_in,
                              void* d_out, int out_size, void* d_ws, size_t ws_size,
                              hipStream_t stream) {
  const float* x0    = (const float*)d_in[0];
  const float* x1    = (const float*)d_in[1];
  const float* x2    = (const float*)d_in[2];
  const float* x3    = (const float*)d_in[3];
  const float* label = (const float*)d_in[4];
  const float* Wg    = (const float*)d_in[5];
  const float* We    = (const float*)d_in[6];
  const float* be    = (const float*)d_in[7];
  float* out = (float*)d_out;

  char* ws = (char*)d_ws;
  unsigned short* WeT    = (unsigned short*)ws;                         // 16 MiB
  unsigned short* fusedB = (unsigned short*)(ws + ((size_t)16 << 20));  // 32 MiB
  float*  gw      = (float*)(ws + ((size_t)48 << 20));                  // 128 KiB
  double* lossAcc = (double*)(ws + ((size_t)49 << 20));                 // 8 B

  fuse_cvt<<<dim3((Bsz * NF) / (256 * 8)), 256, 0, stream>>>(x0, x1, x2, x3, fusedB);
  we_transpose<<<dim3(NF / 64, NP / 64, NE), 256, 0, stream>>>(We, WeT);
  gate_kernel<<<dim3(Bsz / 4), 256, 0, stream>>>(x0, x1, x2, x3, Wg, gw, lossAcc);
  moe_gemm<<<dim3(NP / 128, Bsz / 128), 256, 0, stream>>>(fusedB, WeT, gw, be, label, out, lossAcc);
  finalize_kernel<<<1, 1, 0, stream>>>(lossAcc, out);
}

// Round 3
// 176.256 us; speedup vs baseline: 1.2257x; 1.1398x over previous
//
#include <hip/hip_runtime.h>
#include <stdint.h>

#define Bsz  8192
#define DMOD 512
#define NE   4
#define NP   1024
#define NF   2048

typedef float  f32x4  __attribute__((ext_vector_type(4)));
typedef __bf16 bf16x8 __attribute__((ext_vector_type(8)));
typedef unsigned short u16x8 __attribute__((ext_vector_type(8)));

typedef __attribute__((address_space(3))) void       lds_void;
typedef const __attribute__((address_space(1))) void glb_void;
#define GLOAD16(gp, lp) \
  __builtin_amdgcn_global_load_lds((glb_void*)(gp), (lds_void*)(lp), 16, 0, 0)

__device__ __forceinline__ unsigned short f32_bf16(float f) {
  unsigned int u = __float_as_uint(f);
  u += 0x7FFFu + ((u >> 16) & 1u);   // round-to-nearest-even
  return (unsigned short)(u >> 16);
}

// ---------------- kernel 1: concat + cvt + fused gate (softmax/top2) ----------------
// One block per row: converts the row to bf16 AND computes the 4 gate logits
// (reuses the x data already in registers -> saves a full 67MB re-read).
__global__ __launch_bounds__(256) void fuse_gate(
    const float* __restrict__ x0, const float* __restrict__ x1,
    const float* __restrict__ x2, const float* __restrict__ x3,
    const float* __restrict__ Wg,
    unsigned short* __restrict__ fusedB, float* __restrict__ gw,
    double* __restrict__ lossAcc)
{
  __shared__ float sred[4][4];
  const int b   = blockIdx.x;
  const int tid = threadIdx.x;
  const int f   = tid * 8;
  const float* xm  = (f < 1024) ? (f < 512 ? x0 : x1) : (f < 1536 ? x2 : x3);
  const float* src = xm + (size_t)b * DMOD + (f & 511);
  float4 v0 = *(const float4*)src;
  float4 v1 = *(const float4*)(src + 4);
  u16x8 o;
  o[0] = f32_bf16(v0.x); o[1] = f32_bf16(v0.y); o[2] = f32_bf16(v0.z); o[3] = f32_bf16(v0.w);
  o[4] = f32_bf16(v1.x); o[5] = f32_bf16(v1.y); o[6] = f32_bf16(v1.z); o[7] = f32_bf16(v1.w);
  *(u16x8*)(fusedB + (size_t)b * NF + f) = o;

  float d[4];
  #pragma unroll
  for (int e = 0; e < 4; ++e) {
    const float* w = Wg + e * NF + f;
    d[e] = v0.x * w[0] + v0.y * w[1] + v0.z * w[2] + v0.w * w[3]
         + v1.x * w[4] + v1.y * w[5] + v1.z * w[6] + v1.w * w[7];
  }
  #pragma unroll
  for (int off = 32; off; off >>= 1) {
    #pragma unroll
    for (int e = 0; e < 4; ++e) d[e] += __shfl_xor(d[e], off);
  }
  if ((tid & 63) == 0) {
    #pragma unroll
    for (int e = 0; e < 4; ++e) sred[tid >> 6][e] = d[e];
  }
  __syncthreads();
  if (tid == 0) {
    float a0 = sred[0][0] + sred[1][0] + sred[2][0] + sred[3][0];
    float a1 = sred[0][1] + sred[1][1] + sred[2][1] + sred[3][1];
    float a2 = sred[0][2] + sred[1][2] + sred[2][2] + sred[3][2];
    float a3 = sred[0][3] + sred[1][3] + sred[2][3] + sred[3][3];
    float m  = fmaxf(fmaxf(a0, a1), fmaxf(a2, a3));
    float e0 = expf(a0 - m), e1 = expf(a1 - m), e2 = expf(a2 - m), e3 = expf(a3 - m);
    float inv = 1.f / (e0 + e1 + e2 + e3);
    float p0 = e0 * inv, p1 = e1 * inv, p2 = e2 * inv, p3 = e3 * inv;
    int i1 = 0; float b1 = a0;
    if (a1 > b1) { b1 = a1; i1 = 1; }
    if (a2 > b1) { b1 = a2; i1 = 2; }
    if (a3 > b1) { b1 = a3; i1 = 3; }
    int i2 = -1; float b2 = -3.4e38f;
    if (i1 != 0 && a0 > b2) { b2 = a0; i2 = 0; }
    if (i1 != 1 && a1 > b2) { b2 = a1; i2 = 1; }
    if (i1 != 2 && a2 > b2) { b2 = a2; i2 = 2; }
    if (i1 != 3 && a3 > b2) { b2 = a3; i2 = 3; }
    gw[(size_t)b * 4 + 0] = (i1 == 0 || i2 == 0) ? p0 : 0.f;
    gw[(size_t)b * 4 + 1] = (i1 == 1 || i2 == 1) ? p1 : 0.f;
    gw[(size_t)b * 4 + 2] = (i1 == 2 || i2 == 2) ? p2 : 0.f;
    gw[(size_t)b * 4 + 3] = (i1 == 3 || i2 == 3) ? p3 : 0.f;
    if (b == 0) *lossAcc = 0.0;
  }
}

// ---------------- kernel 2: We [E][F][P] f32 -> We_T [E][P][F] bf16 ----------------
__global__ __launch_bounds__(256) void we_transpose(
    const float* __restrict__ We, unsigned short* __restrict__ WeT)
{
  __shared__ float t[64][65];
  const int e  = blockIdx.z;
  const int tf = blockIdx.x * 64;
  const int tp = blockIdx.y * 64;
  const int t4 = threadIdx.x * 4;
  const float* src = We + ((size_t)e * NF + tf) * NP + tp;
  #pragma unroll
  for (int i = 0; i < 4; ++i) {
    int li = i * 1024 + t4;
    int r = li >> 6, c = li & 63;
    float4 v = *(const float4*)(src + (size_t)r * NP + c);
    t[c][r] = v.x; t[c+1][r] = v.y; t[c+2][r] = v.z; t[c+3][r] = v.w;
  }
  __syncthreads();
  unsigned short* dst = WeT + ((size_t)e * NP + tp) * NF + tf;
  #pragma unroll
  for (int i = 0; i < 4; ++i) {
    int li = i * 1024 + t4;
    int r = li >> 6, c = li & 63;
    ushort4 o;
    o.x = f32_bf16(t[r][c]);   o.y = f32_bf16(t[r][c+1]);
    o.z = f32_bf16(t[r][c+2]); o.w = f32_bf16(t[r][c+3]);
    *(ushort4*)(dst + (size_t)r * NF + c) = o;
  }
}

// ---------------- kernel 3: pipelined per-expert GEMM ----------------
// Depth-2 software pipeline over a flat 128-step (4 experts x 32 K-tiles) stream.
// Counted vmcnt(8) (one 8-load batch stays in flight across barriers), raw
// s_barrier (no compiler vmcnt(0) drain), LDS double-buffer, XCD-chunked
// block swizzle. Gate weights pre-staged in LDS so the loop has no stray
// global loads perturbing vmcnt bookkeeping.
__global__ __launch_bounds__(256, 2) void moe_gemm(
    const unsigned short* __restrict__ fusedB,   // [B][F] bf16
    const unsigned short* __restrict__ WeT,      // [E][P][F] bf16
    const float* __restrict__ gw,                // [B][E]
    const float* __restrict__ be,                // [E][P]
    const float* __restrict__ label,             // [B][P]
    float* __restrict__ out,                     // [0]=loss, [1..] preds
    double* __restrict__ lossAcc)
{
  __shared__ __align__(16) unsigned short As[2][128 * 64];
  __shared__ __align__(16) unsigned short Bs[2][128 * 64];
  __shared__ float gwS[128][4];
  __shared__ float red[4];

  const int tid  = threadIdx.x;
  const int l    = tid & 63;
  const int wave = tid >> 6;
  const int wr   = wave >> 1;
  const int wc   = wave & 1;
  const int lrow = l & 15;
  const int g4   = l >> 4;
  const int lr8  = l >> 3;   // lane's row within an 8-row staging stripe
  const int lc8  = l & 7;    // lane's linear LDS chunk within the row

  // XCD-chunked swizzle: XCD c (= hw linear id % 8) gets 64 consecutive
  // logical blocks = 8 A-panel rows x all 8 cols (A ws = 4MB = one L2).
  const int bid  = (int)blockIdx.x;
  const int swz  = (bid & 7) * 64 + (bid >> 3);
  const int pcol = (swz & 7) * 128;
  const int brow = (swz >> 3) * 128;

  // gate weights -> LDS (before any pipeline loads/barriers)
  if (tid < 128) *(float4*)gwS[tid] = *(const float4*)(gw + (size_t)(brow + tid) * 4);
  __syncthreads();

  f32x4 accT[4][4], accE[4][4];
  #pragma unroll
  for (int m = 0; m < 4; ++m)
    #pragma unroll
    for (int n = 0; n < 4; ++n) {
      accT[m][n] = f32x4{0.f, 0.f, 0.f, 0.f};
      accE[m][n] = f32x4{0.f, 0.f, 0.f, 0.f};
    }

  // stage flat step t (e = t>>5, k-tile = t&31) into buffer buf: 8 loads/wave
  auto STAGE = [&](int t, int buf) {
    const int e  = t >> 5;
    const int k0 = (t & 31) << 6;
    const unsigned short* Ab = fusedB + (size_t)brow * NF + k0;
    const unsigned short* Bb = WeT + ((size_t)e * NP + pcol) * NF + k0;
    #pragma unroll
    for (int i = 0; i < 4; ++i) {
      const int r0   = wave * 32 + i * 8;          // wave-uniform stripe base
      const int trow = r0 + lr8;
      const int ch   = lc8 ^ (trow & 7);           // inverse-swizzled source chunk
      GLOAD16(Ab + (size_t)trow * NF + ch * 8, (char*)(&As[buf][r0 * 64]));
      GLOAD16(Bb + (size_t)trow * NF + ch * 8, (char*)(&Bs[buf][r0 * 64]));
    }
  };

  auto COMPUTE = [&](int buf) {
    #pragma unroll
    for (int ks = 0; ks < 2; ++ks) {
      bf16x8 af[4], bfr[4];
      #pragma unroll
      for (int m = 0; m < 4; ++m) {
        const int fr = wr * 64 + m * 16 + lrow;
        const int ch = ((g4 + ks * 4) ^ (fr & 7)) * 8;
        af[m] = __builtin_bit_cast(bf16x8, *(const u16x8*)(&As[buf][fr * 64 + ch]));
      }
      #pragma unroll
      for (int n = 0; n < 4; ++n) {
        const int fr = wc * 64 + n * 16 + lrow;
        const int ch = ((g4 + ks * 4) ^ (fr & 7)) * 8;
        bfr[n] = __builtin_bit_cast(bf16x8, *(const u16x8*)(&Bs[buf][fr * 64 + ch]));
      }
      #pragma unroll
      for (int m = 0; m < 4; ++m)
        #pragma unroll
        for (int n = 0; n < 4; ++n)
          accE[m][n] = __builtin_amdgcn_mfma_f32_16x16x32_bf16(af[m], bfr[n], accE[m][n], 0, 0, 0);
    }
  };

  auto FOLD = [&](int e) {   // register-only: accT += w[row,e] * accE; accE = 0
    #pragma unroll
    for (int m = 0; m < 4; ++m)
      #pragma unroll
      for (int r = 0; r < 4; ++r) {
        const float wv = gwS[wr * 64 + m * 16 + g4 * 4 + r][e];
        #pragma unroll
        for (int n = 0; n < 4; ++n) {
          accT[m][n][r] += wv * accE[m][n][r];
          accE[m][n][r] = 0.f;
        }
      }
  };

  STAGE(0, 0);
  STAGE(1, 1);

  for (int t = 0; t < 128; ++t) {
    const int buf = t & 1;
    // batches in flight newer than t: exactly one (t+1) for t<=126, none at t=127
    if (t == 127) asm volatile("s_waitcnt vmcnt(0)" ::: "memory");
    else          asm volatile("s_waitcnt vmcnt(8)" ::: "memory");
    __builtin_amdgcn_s_barrier();          // all waves' batch-t loads landed
    COMPUTE(buf);
    if ((t & 31) == 31) FOLD(t >> 5);
    __builtin_amdgcn_sched_barrier(0);     // pin ds_reads+MFMAs before the barrier
    __builtin_amdgcn_s_barrier();          // all waves done reading buf
    if (t < 126) STAGE(t + 2, buf);        // overwrite freed buffer
  }

  // epilogue: bias, store preds, fused MSE partial
  float lsum = 0.f;
  #pragma unroll
  for (int m = 0; m < 4; ++m) {
    #pragma unroll
    for (int r = 0; r < 4; ++r) {
      const int lrowi = wr * 64 + m * 16 + g4 * 4 + r;
      const int grow  = brow + lrowi;
      const float w0 = gwS[lrowi][0];
      const float w1 = gwS[lrowi][1];
      const float w2 = gwS[lrowi][2];
      const float w3 = gwS[lrowi][3];
      #pragma unroll
      for (int n = 0; n < 4; ++n) {
        const int gcol = pcol + wc * 64 + n * 16 + lrow;
        float bias = w0 * be[gcol] + w1 * be[NP + gcol] + w2 * be[2 * NP + gcol] + w3 * be[3 * NP + gcol];
        float pred = accT[m][n][r] + bias;
        out[1 + (size_t)grow * NP + gcol] = pred;
        float d = pred - label[(size_t)grow * NP + gcol];
        lsum += d * d;
      }
    }
  }
  #pragma unroll
  for (int off = 32; off; off >>= 1) lsum += __shfl_xor(lsum, off);
  if (l == 0) red[wave] = lsum;
  __syncthreads();
  if (tid == 0) {
    double s = (double)red[0] + (double)red[1] + (double)red[2] + (double)red[3];
    atomicAdd(lossAcc, s);
  }
}

// ---------------- kernel 4: finalize loss ----------------
__global__ void finalize_kernel(const double* __restrict__ lossAcc, float* __restrict__ out) {
  out[0] = (float)(*lossAcc * (1.0 / ((double)Bsz * (double)NP)));
}

extern "C" void kernel_launch(void* const* d_in, const int* in_sizes, int n_in,
                              void* d_out, int out_size, void* d_ws, size_t ws_size,
                              hipStream_t stream) {
  const float* x0    = (const float*)d_in[0];
  const float* x1    = (const float*)d_in[1];
  const float* x2    = (const float*)d_in[2];
  const float* x3    = (const float*)d_in[3];
  const float* label = (const float*)d_in[4];
  const float* Wg    = (const float*)d_in[5];
  const float* We    = (const float*)d_in[6];
  const float* be    = (const float*)d_in[7];
  float* out = (float*)d_out;

  char* ws = (char*)d_ws;
  unsigned short* WeT    = (unsigned short*)ws;                         // 16 MiB
  unsigned short* fusedB = (unsigned short*)(ws + ((size_t)16 << 20));  // 32 MiB
  float*  gw      = (float*)(ws + ((size_t)48 << 20));                  // 128 KiB
  double* lossAcc = (double*)(ws + ((size_t)49 << 20));                 // 8 B

  fuse_gate<<<dim3(Bsz), 256, 0, stream>>>(x0, x1, x2, x3, Wg, fusedB, gw, lossAcc);
  we_transpose<<<dim3(NF / 64, NP / 64, NE), 256, 0, stream>>>(We, WeT);
  moe_gemm<<<dim3(512), 256, 0, stream>>>(fusedB, WeT, gw, be, label, out, lossAcc);
  finalize_kernel<<<1, 1, 0, stream>>>(lossAcc, out);
}